// Round 10
// baseline (636.732 us; speedup 1.0000x reference)
//
#include <hip/hip_runtime.h>
#include <cstdint>
#include <cstddef>

#define NEG_SLOPE 0.2f
#define NXCD 8

typedef _Float16 f16x8 __attribute__((ext_vector_type(8)));
typedef float f32x4v __attribute__((ext_vector_type(4)));

__device__ __forceinline__ unsigned enc_f(float f) {
  unsigned u = __float_as_uint(f);
  return (u & 0x80000000u) ? ~u : (u | 0x80000000u);
}
__device__ __forceinline__ float dec_f(unsigned u) {
  return (u & 0x80000000u) ? __uint_as_float(u ^ 0x80000000u) : __uint_as_float(~u);
}
__device__ __forceinline__ int xcc_id() {
  int x;
  asm("s_getreg_b32 %0, hwreg(HW_REG_XCC_ID, 0, 4)" : "=s"(x));
  return x & (NXCD - 1);
}

#define AST 136
#define WST 136
#define HST 132
#define SMEM_BYTES (64 * AST * 2 + 128 * WST * 2)

// ---------------- batch boundaries + zero partitioned counts + zero maxPart ----------------
__global__ void k_bounds(const int* __restrict__ batch, int N, int B,
                         int* __restrict__ gstart, unsigned* __restrict__ maxPart,
                         int* __restrict__ c) {
  int n = blockIdx.x * blockDim.x + threadIdx.x;
  if (n < 768) maxPart[n] = 0u;
  if (n >= N) return;
#pragma unroll
  for (int p = 0; p < NXCD; p++) c[(size_t)p * N + n] = 0;
  int cur = batch[n];
  if (n == 0) {
    for (int g = 0; g <= cur; g++) gstart[g] = 0;
  } else {
    int prev = batch[n - 1];
    for (int g = prev + 1; g <= cur; g++) gstart[g] = n;
  }
  if (n == N - 1) {
    for (int g = cur + 1; g <= B; g++) gstart[g] = N;
  }
}

// ---------------- CSR: rank via XCD-local (workgroup-scope) returning atomicAdd ----------------
// Each XCD's waves hit only their own count copy -> RMW stays in the local L2 (no fabric trip).
// Partition id is tagged into rank bits [24..26] for the fill pass.
__global__ void k_count_rank(const int* __restrict__ dst, int E, int N,
                             int* __restrict__ c, int* __restrict__ rank) {
  int p = xcc_id();
  int e = blockIdx.x * blockDim.x + threadIdx.x;
  if (e < E) {
    int r = __hip_atomic_fetch_add(&c[(size_t)p * N + dst[e]], 1,
                                   __ATOMIC_RELAXED, __HIP_MEMORY_SCOPE_WORKGROUP);
    rank[e] = r | (p << 24);
  }
}

// per-node total (1 self loop + NXCD partials) -> inclusive block scan
__global__ __launch_bounds__(1024) void k_scan1(const int* __restrict__ c, int N,
                                                int* __restrict__ row_ptr, int* __restrict__ part) {
  __shared__ int tmp[1024];
  int t = threadIdx.x;
  int i = blockIdx.x * 1024 + t;
  int v = 0;
  if (i < N) {
    v = 1;
#pragma unroll
    for (int p = 0; p < NXCD; p++) v += c[(size_t)p * N + i];
  }
  tmp[t] = v;
  __syncthreads();
  for (int off = 1; off < 1024; off <<= 1) {
    int u = (t >= off) ? tmp[t - off] : 0;
    __syncthreads();
    tmp[t] += u;
    __syncthreads();
  }
  if (i < N) row_ptr[i + 1] = tmp[t];
  if (t == 1023) part[blockIdx.x] = tmp[t];
}

// finalize row_ptr + per-(partition,node) bases + self-loop placement
__global__ __launch_bounds__(1024) void k_scan3(int* __restrict__ row_ptr,
                                                const int* __restrict__ part, int N,
                                                const int* __restrict__ c,
                                                int* __restrict__ base, int* __restrict__ col) {
  __shared__ int s_off;
  int bi = blockIdx.x;
  if (threadIdx.x == 0) {
    int run = 0;
    for (int b = 0; b < bi; b++) run += part[b];
    s_off = run;
  }
  __syncthreads();
  int i = bi * 1024 + threadIdx.x;
  if (i < N) {
    int v = row_ptr[i + 1] + s_off;
    row_ptr[i + 1] = v;
    int node = i + 1;
    if (node < N) {
      col[v] = node;  // self loop first in row of node i+1
      int b = v + 1;
#pragma unroll
      for (int p = 0; p < NXCD; p++) {
        base[(size_t)p * N + node] = b;
        b += c[(size_t)p * N + node];
      }
    }
    if (i == 0) {
      row_ptr[0] = 0;
      col[0] = 0;  // node 0 self loop
      int b = 1;
#pragma unroll
      for (int p = 0; p < NXCD; p++) {
        base[(size_t)p * N] = b;
        b += c[(size_t)p * N];
      }
    }
  }
}

// ---------------- fp16-MFMA GEMM body (64-row tile): hb(fp16)=A@W ; s,d ; partial max(s) ---------
__device__ __forceinline__ void gemm_body(char* smem, float* redmax, int bx,
                                          const float* __restrict__ A32,
                                          const unsigned short* __restrict__ A16,
                                          const float* __restrict__ W,
                                          unsigned short* __restrict__ hb,
                                          const float* __restrict__ asrc,
                                          const float* __restrict__ adst,
                                          float* __restrict__ sv, float* __restrict__ dv,
                                          unsigned* __restrict__ maxSlot, int M) {
  _Float16* Ah = (_Float16*)smem;                       // [64][AST]
  _Float16* Wt = (_Float16*)(smem + 64 * AST * 2);      // [128][WST] transposed W
  float*    hS = (float*)(smem + 64 * AST * 2);         // [64][HST] aliases Wt after mfma
  int t = threadIdx.x;
  int rowbase = bx * 64;

  if (A16) {
    for (int i = t; i < 64 * 16; i += 256) {
      int r = i >> 4, c8 = (i & 15) << 3;
      int gr = rowbase + r;
      uint4 v = make_uint4(0u, 0u, 0u, 0u);
      if (gr < M) v = *(const uint4*)&A16[(size_t)gr * 128 + c8];
      *(uint4*)&Ah[r * AST + c8] = v;
    }
  } else {
    for (int i = t; i < 64 * 32; i += 256) {
      int r = i >> 5, c4 = (i & 31) << 2;
      int gr = rowbase + r;
      float4 v = make_float4(0.f, 0.f, 0.f, 0.f);
      if (gr < M) v = *(const float4*)&A32[(size_t)gr * 128 + c4];
      _Float16 tmp[4] = {(_Float16)v.x, (_Float16)v.y, (_Float16)v.z, (_Float16)v.w};
      *(short4*)&Ah[r * AST + c4] = *(short4*)tmp;
    }
  }
  for (int i = t; i < 128 * 32; i += 256) {
    int r = i >> 5, c4 = (i & 31) << 2;
    float4 v = *(const float4*)&W[(size_t)r * 128 + c4];
    Wt[(c4 + 0) * WST + r] = (_Float16)v.x;
    Wt[(c4 + 1) * WST + r] = (_Float16)v.y;
    Wt[(c4 + 2) * WST + r] = (_Float16)v.z;
    Wt[(c4 + 3) * WST + r] = (_Float16)v.w;
  }
  __syncthreads();

  int wave = t >> 6, lane = t & 63, quad = lane >> 4, l15 = lane & 15;
  f32x4v acc[4][2];
#pragma unroll
  for (int mt = 0; mt < 4; mt++)
#pragma unroll
    for (int nt = 0; nt < 2; nt++) {
      acc[mt][nt][0] = 0.f; acc[mt][nt][1] = 0.f; acc[mt][nt][2] = 0.f; acc[mt][nt][3] = 0.f;
    }

#pragma unroll
  for (int s = 0; s < 4; s++) {
    int k0 = (s << 5) + (quad << 3);
    f16x8 af[4], bf[2];
#pragma unroll
    for (int mt = 0; mt < 4; mt++)
      af[mt] = *(f16x8*)&Ah[(mt * 16 + l15) * AST + k0];
#pragma unroll
    for (int nt = 0; nt < 2; nt++)
      bf[nt] = *(f16x8*)&Wt[(wave * 32 + nt * 16 + l15) * WST + k0];
#pragma unroll
    for (int mt = 0; mt < 4; mt++)
#pragma unroll
      for (int nt = 0; nt < 2; nt++)
        acc[mt][nt] = __builtin_amdgcn_mfma_f32_16x16x32_f16(af[mt], bf[nt], acc[mt][nt], 0, 0, 0);
  }
  __syncthreads();

#pragma unroll
  for (int mt = 0; mt < 4; mt++)
#pragma unroll
    for (int nt = 0; nt < 2; nt++)
#pragma unroll
      for (int rr = 0; rr < 4; rr++)
        hS[(mt * 16 + quad * 4 + rr) * HST + wave * 32 + nt * 16 + l15] = acc[mt][nt][rr];
  __syncthreads();

  int tx = t & 31, ty = t >> 5;
  float4 av  = *(const float4*)&asrc[tx * 4];
  float4 adv = *(const float4*)&adst[tx * 4];
  float wmax = -1e30f;
#pragma unroll
  for (int r8 = 0; r8 < 8; r8++) {
    int row = r8 * 8 + ty;
    int gr = rowbase + row;
    float4 hv = *(float4*)&hS[row * HST + tx * 4];
    float ps = hv.x * av.x + hv.y * av.y + hv.z * av.z + hv.w * av.w;
    float pd = hv.x * adv.x + hv.y * adv.y + hv.z * adv.z + hv.w * adv.w;
#pragma unroll
    for (int mask = 16; mask; mask >>= 1) {
      ps += __shfl_xor(ps, mask);
      pd += __shfl_xor(pd, mask);
    }
    if (gr < M) {
      _Float16 hq[4] = {(_Float16)hv.x, (_Float16)hv.y, (_Float16)hv.z, (_Float16)hv.w};
      *(uint2*)&hb[(size_t)gr * 128 + tx * 4] = *(uint2*)hq;
      if (tx == 0) { sv[gr] = ps; dv[gr] = pd; wmax = fmaxf(wmax, ps); }
    }
  }
#pragma unroll
  for (int mask = 32; mask; mask >>= 1) wmax = fmaxf(wmax, __shfl_xor(wmax, mask));
  if ((t & 63) == 0) redmax[t >> 6] = wmax;
  __syncthreads();
  if (t == 0) {
    float mx = fmaxf(fmaxf(redmax[0], redmax[1]), fmaxf(redmax[2], redmax[3]));
    atomicMax(&maxSlot[bx & 255], enc_f(mx));
  }
}

// ---------------- FUSED: CSR edge fill (scatter) || layer-0 GEMM, stride-interleaved ------------
__global__ __launch_bounds__(256) void k_fill_gemm(const int* __restrict__ src,
                                                   const int* __restrict__ dst,
                                                   const int* __restrict__ rank, int E, int N,
                                                   const int* __restrict__ base,
                                                   int* __restrict__ col,
                                                   const float* __restrict__ A32,
                                                   const float* __restrict__ W,
                                                   unsigned short* __restrict__ hb,
                                                   const float* __restrict__ asrc,
                                                   const float* __restrict__ adst,
                                                   float* __restrict__ sv, float* __restrict__ dv,
                                                   unsigned* __restrict__ maxSlot,
                                                   int Gg, int stride) {
  __shared__ __align__(16) char smem[SMEM_BYTES];
  __shared__ float redmax[4];
  int b = (int)blockIdx.x;
  bool isGemm = ((b % stride) == 0) && ((b / stride) < Gg);
  if (isGemm) {
    gemm_body(smem, redmax, b / stride, A32, (const unsigned short*)nullptr, W,
              hb, asrc, adst, sv, dv, maxSlot, N);
  } else {
    int g = min(b / stride + 1, Gg);  // gemm blocks before b
    int i = (b - g) * 256 + threadIdx.x;
    if (i < E) {
      int r = rank[i];
      int p = r >> 24;
      r &= 0xFFFFFF;
      col[base[(size_t)p * N + dst[i]] + r] = src[i];
    }
  }
}

// ---------------- standalone fused GEMM for layers 1,2 ----------------
__global__ __launch_bounds__(256) void k_gemm_fused(const unsigned short* __restrict__ A16,
                                                    const float* __restrict__ W,
                                                    unsigned short* __restrict__ hb,
                                                    const float* __restrict__ asrc,
                                                    const float* __restrict__ adst,
                                                    float* __restrict__ sv, float* __restrict__ dv,
                                                    unsigned* __restrict__ maxSlot, int M) {
  __shared__ __align__(16) char smem[SMEM_BYTES];
  __shared__ float redmax[4];
  gemm_body(smem, redmax, (int)blockIdx.x, (const float*)nullptr, A16, W,
            hb, asrc, adst, sv, dv, maxSlot, M);
}

// ---------------- segment-softmax aggregation: 1 wave/node, 4 groups, 2-deep prefetch ------------
__global__ __launch_bounds__(256) void k_agg(const unsigned short* __restrict__ hb,
                                             const float* __restrict__ sv,
                                             const float* __restrict__ dv,
                                             const int* __restrict__ row_ptr,
                                             const int* __restrict__ col,
                                             const float* __restrict__ bias,
                                             const unsigned* __restrict__ maxSlot,
                                             unsigned short* __restrict__ out16,
                                             int N, int relu) {
  int wid = (int)((blockIdx.x * (size_t)blockDim.x + threadIdx.x) >> 6);
  int lane = threadIdx.x & 63;
  if (wid >= N) return;

  unsigned mp = max(max(maxSlot[lane], maxSlot[lane + 64]),
                    max(maxSlot[lane + 128], maxSlot[lane + 192]));
#pragma unroll
  for (int off = 32; off; off >>= 1) mp = max(mp, __shfl_xor(mp, off));
  float maxS = dec_f(mp);

  int beg = row_ptr[wid], end = row_ptr[wid + 1];
  float dn = dv[wid];
  float m = maxS + dn;
  m = (m > 0.f) ? m : NEG_SLOPE * m;  // upper bound on all incoming e (leaky_relu monotone)

  int g = lane >> 4, sub = lane & 15;
  const uint32_t* hbu = (const uint32_t*)hb;
  float acc[8];
#pragma unroll
  for (int k = 0; k < 8; k++) acc[k] = 0.f;
  float dsum = 0.f;

  int j = beg + g;
  float w0 = 0.f, w1 = 0.f;
  uint4 h0 = make_uint4(0u, 0u, 0u, 0u), h1 = make_uint4(0u, 0u, 0u, 0u);
  if (j < end) {
    int sn = col[j];
    float e = sv[sn] + dn;
    e = (e > 0.f) ? e : NEG_SLOPE * e;
    w0 = __expf(e - m);
    h0 = *(const uint4*)(hbu + (size_t)sn * 64 + sub * 4);
  }
  if (j + 4 < end) {
    int sn = col[j + 4];
    float e = sv[sn] + dn;
    e = (e > 0.f) ? e : NEG_SLOPE * e;
    w1 = __expf(e - m);
    h1 = *(const uint4*)(hbu + (size_t)sn * 64 + sub * 4);
  }
  j += 8;
  while (j < end) {
    dsum += w0;
    {
      const _Float16* hp = (const _Float16*)&h0;
#pragma unroll
      for (int k = 0; k < 8; k++) acc[k] += w0 * (float)hp[k];
    }
    w0 = w1; h0 = h1;
    int sn = col[j];
    float e = sv[sn] + dn;
    e = (e > 0.f) ? e : NEG_SLOPE * e;
    w1 = __expf(e - m);
    h1 = *(const uint4*)(hbu + (size_t)sn * 64 + sub * 4);
    j += 4;
  }
  {
    dsum += w0;
    const _Float16* hp = (const _Float16*)&h0;
#pragma unroll
    for (int k = 0; k < 8; k++) acc[k] += w0 * (float)hp[k];
  }
  {
    dsum += w1;
    const _Float16* hp = (const _Float16*)&h1;
#pragma unroll
    for (int k = 0; k < 8; k++) acc[k] += w1 * (float)hp[k];
  }

  dsum += __shfl_xor(dsum, 16);
  dsum += __shfl_xor(dsum, 32);
#pragma unroll
  for (int k = 0; k < 8; k++) {
    acc[k] += __shfl_xor(acc[k], 16);
    acc[k] += __shfl_xor(acc[k], 32);
  }
  if (lane < 16) {
    float inv = 1.f / dsum;
    float o[8];
    const float* bp = &bias[sub * 8];
#pragma unroll
    for (int k = 0; k < 8; k++) {
      o[k] = acc[k] * inv + bp[k];
      if (relu) o[k] = fmaxf(o[k], 0.f);
    }
    _Float16 q[8];
#pragma unroll
    for (int k = 0; k < 8; k++) q[k] = (_Float16)o[k];
    *(uint4*)&out16[(size_t)wid * 128 + sub * 8] = *(uint4*)q;
  }
}

// ---------------- mean pool (fp16 in) + relu, 4-way node-segment split ----------------
__global__ __launch_bounds__(256) void k_pool(const unsigned short* __restrict__ h16,
                                              const int* __restrict__ gstart,
                                              float* __restrict__ pooled, int B) {
  __shared__ float red[4][128];
  int b = blockIdx.x, t = threadIdx.x;
  int c = t & 63, seg = t >> 6;
  int s0 = gstart[b], s1 = gstart[b + 1];
  int cnt = s1 - s0;
  int per = (cnt + 3) >> 2;
  int n0 = s0 + seg * per;
  int n1 = min(n0 + per, s1);
  const uint32_t* hu = (const uint32_t*)h16;
  float a0 = 0.f, a1 = 0.f;
  for (int n = n0; n < n1; n++) {
    union { uint32_t u; _Float16 h[2]; } cv;
    cv.u = hu[(size_t)n * 64 + c];
    a0 += (float)cv.h[0];
    a1 += (float)cv.h[1];
  }
  if (seg) { red[seg][2 * c] = a0; red[seg][2 * c + 1] = a1; }
  __syncthreads();
  if (seg == 0) {
    a0 += red[1][2 * c] + red[2][2 * c] + red[3][2 * c];
    a1 += red[1][2 * c + 1] + red[2][2 * c + 1] + red[3][2 * c + 1];
    float inv = 1.f / (float)(cnt > 0 ? cnt : 1);
    pooled[b * 128 + 2 * c]     = fmaxf(a0 * inv, 0.f);
    pooled[b * 128 + 2 * c + 1] = fmaxf(a1 * inv, 0.f);
  }
}

// ---------------- fused MLP head ----------------
__global__ __launch_bounds__(256) void k_mlp(const float* __restrict__ pooled,
                                             const float* __restrict__ Wf1,
                                             const float* __restrict__ bf1,
                                             const float* __restrict__ Wf2,
                                             const float* __restrict__ bf2,
                                             float* __restrict__ out, int B) {
  __shared__ float P[4][128];
  __shared__ float H1[4][1024];
  __shared__ float R[4][128];
  int t = threadIdx.x;
  int g0 = blockIdx.x * 4;

  for (int i = t; i < 4 * 128; i += 256) {
    int gi = i >> 7, c = i & 127;
    P[gi][c] = (g0 + gi < B) ? pooled[(size_t)(g0 + gi) * 128 + c] : 0.f;
  }
  __syncthreads();

#pragma unroll
  for (int cb = 0; cb < 4; cb++) {
    int c = cb * 256 + t;
    float a0 = 0.f, a1 = 0.f, a2 = 0.f, a3 = 0.f;
    for (int k = 0; k < 128; k++) {
      float w = Wf1[(size_t)k * 1024 + c];
      a0 += P[0][k] * w; a1 += P[1][k] * w; a2 += P[2][k] * w; a3 += P[3][k] * w;
    }
    float b = bf1[c];
    H1[0][c] = fmaxf(a0 + b, 0.f);
    H1[1][c] = fmaxf(a1 + b, 0.f);
    H1[2][c] = fmaxf(a2 + b, 0.f);
    H1[3][c] = fmaxf(a3 + b, 0.f);
  }
  __syncthreads();

  int c = t & 127, hh = t >> 7;
  float a0 = 0.f, a1 = 0.f, a2 = 0.f, a3 = 0.f;
  int k0 = hh * 512;
  for (int k = k0; k < k0 + 512; k++) {
    float w = Wf2[(size_t)k * 128 + c];
    a0 += H1[0][k] * w; a1 += H1[1][k] * w; a2 += H1[2][k] * w; a3 += H1[3][k] * w;
  }
  if (hh == 1) { R[0][c] = a0; R[1][c] = a1; R[2][c] = a2; R[3][c] = a3; }
  __syncthreads();
  if (hh == 0) {
    float b = bf2[c];
    float o0 = a0 + R[0][c] + b;
    float o1 = a1 + R[1][c] + b;
    float o2 = a2 + R[2][c] + b;
    float o3 = a3 + R[3][c] + b;
    if (g0 + 0 < B) out[(size_t)(g0 + 0) * 128 + c] = o0;
    if (g0 + 1 < B) out[(size_t)(g0 + 1) * 128 + c] = o1;
    if (g0 + 2 < B) out[(size_t)(g0 + 2) * 128 + c] = o2;
    if (g0 + 3 < B) out[(size_t)(g0 + 3) * 128 + c] = o3;
  }
}

extern "C" void kernel_launch(void* const* d_in, const int* in_sizes, int n_in,
                              void* d_out, int out_size, void* d_ws, size_t ws_size,
                              hipStream_t stream) {
  const float* x     = (const float*)d_in[0];
  const int*   ei    = (const int*)d_in[1];
  const int*   batch = (const int*)d_in[3];
  const float* W1 = (const float*)d_in[4];
  const float* as1 = (const float*)d_in[5];
  const float* ad1 = (const float*)d_in[6];
  const float* b1 = (const float*)d_in[7];
  const float* W2 = (const float*)d_in[8];
  const float* as2 = (const float*)d_in[9];
  const float* ad2 = (const float*)d_in[10];
  const float* b2 = (const float*)d_in[11];
  const float* W3 = (const float*)d_in[12];
  const float* as3 = (const float*)d_in[13];
  const float* ad3 = (const float*)d_in[14];
  const float* b3 = (const float*)d_in[15];
  const float* Wf1 = (const float*)d_in[16];
  const float* bf1 = (const float*)d_in[17];
  const float* Wf2 = (const float*)d_in[18];
  const float* bf2 = (const float*)d_in[19];

  const int N = in_sizes[0] / 128;
  const int E = in_sizes[1] / 2;
  const int B = out_size / 128;

  char* base_ws = (char*)d_ws;
  size_t off = 0;
  auto carve = [&](size_t bytes) -> void* {
    off = (off + 255) & ~(size_t)255;
    void* p = base_ws + off;
    off += bytes;
    return p;
  };
  int* c        = (int*)carve((size_t)NXCD * N * 4);
  int* base     = (int*)carve((size_t)NXCD * N * 4);
  int* row_ptr  = (int*)carve((size_t)(N + 1) * 4);
  int* rank     = (int*)carve((size_t)E * 4);
  int* col      = (int*)carve((size_t)(E + N) * 4);
  int* part     = (int*)carve(1024 * 4);
  int* gstart   = (int*)carve((size_t)(B + 1) * 4);
  unsigned* maxPart = (unsigned*)carve(768 * 4);
  float* sbuf   = (float*)carve((size_t)N * 4);
  float* dbuf   = (float*)carve((size_t)N * 4);
  unsigned short* hb  = (unsigned short*)carve((size_t)N * 128 * 2);
  unsigned short* a16 = (unsigned short*)carve((size_t)N * 128 * 2);
  float* pooled = (float*)carve((size_t)B * 128 * 4);

  const int* srcp = ei;
  const int* dstp = ei + E;
  const int nb = (N + 1023) / 1024;
  const int Gg = (N + 63) / 64;             // gemm tiles per layer
  const int Gf = (E + 255) / 256;           // fill blocks (edges only; self loops in scan3)
  const int stride = (Gf + Gg) / Gg;        // gemm every `stride` blocks, guaranteed in-grid

  hipLaunchKernelGGL(k_bounds, dim3((N + 255) / 256), dim3(256), 0, stream,
                     batch, N, B, gstart, maxPart, c);
  hipLaunchKernelGGL(k_count_rank, dim3((E + 255) / 256), dim3(256), 0, stream,
                     dstp, E, N, c, rank);
  hipLaunchKernelGGL(k_scan1, dim3(nb), dim3(1024), 0, stream, c, N, row_ptr, part);
  hipLaunchKernelGGL(k_scan3, dim3(nb), dim3(1024), 0, stream, row_ptr, part, N, c, base, col);

  // edge fill (CSR scatter) || gemm layer 0 — independent, stride-interleaved in one grid
  hipLaunchKernelGGL(k_fill_gemm, dim3(Gf + Gg), dim3(256), 0, stream,
                     srcp, dstp, rank, E, N, base, col,
                     x, W1, hb, as1, ad1, sbuf, dbuf, maxPart + 0 * 256, Gg, stride);

  hipLaunchKernelGGL(k_agg, dim3((N + 3) / 4), dim3(256), 0, stream,
                     hb, sbuf, dbuf, row_ptr, col, b1, maxPart + 0 * 256, a16, N, 0);

  hipLaunchKernelGGL(k_gemm_fused, dim3(Gg), dim3(256), 0, stream,
                     a16, W2, hb, as2, ad2, sbuf, dbuf, maxPart + 1 * 256, N);
  hipLaunchKernelGGL(k_agg, dim3((N + 3) / 4), dim3(256), 0, stream,
                     hb, sbuf, dbuf, row_ptr, col, b2, maxPart + 1 * 256, a16, N, 1);

  hipLaunchKernelGGL(k_gemm_fused, dim3(Gg), dim3(256), 0, stream,
                     a16, W3, hb, as3, ad3, sbuf, dbuf, maxPart + 2 * 256, N);
  hipLaunchKernelGGL(k_agg, dim3((N + 3) / 4), dim3(256), 0, stream,
                     hb, sbuf, dbuf, row_ptr, col, b3, maxPart + 2 * 256, a16, N, 1);

  hipLaunchKernelGGL(k_pool, dim3(B), dim3(256), 0, stream, a16, gstart, pooled, B);
  hipLaunchKernelGGL(k_mlp, dim3((B + 3) / 4), dim3(256), 0, stream,
                     pooled, Wf1, bf1, Wf2, bf2, (float*)d_out, B);
}

// Round 11
// 527.943 us; speedup vs baseline: 1.2061x; 1.2061x over previous
//
#include <hip/hip_runtime.h>
#include <cstdint>
#include <cstddef>

#define NEG_SLOPE 0.2f

typedef _Float16 f16x8 __attribute__((ext_vector_type(8)));
typedef float f32x4v __attribute__((ext_vector_type(4)));

__device__ __forceinline__ unsigned enc_f(float f) {
  unsigned u = __float_as_uint(f);
  return (u & 0x80000000u) ? ~u : (u | 0x80000000u);
}
__device__ __forceinline__ float dec_f(unsigned u) {
  return (u & 0x80000000u) ? __uint_as_float(u ^ 0x80000000u) : __uint_as_float(~u);
}

#define AST 136
#define WST 136
#define HST 132
#define SMEM_BYTES (64 * AST * 2 + 128 * WST * 2)

// ---------------- batch boundaries + zero counts + zero maxPart ----------------
__global__ void k_bounds(const int* __restrict__ batch, int N, int B,
                         int* __restrict__ gstart, unsigned* __restrict__ maxPart,
                         int* __restrict__ counts) {
  int n = blockIdx.x * blockDim.x + threadIdx.x;
  if (n < 768) maxPart[n] = 0u;
  if (n >= N) return;
  counts[n] = 0;
  int cur = batch[n];
  if (n == 0) {
    for (int g = 0; g <= cur; g++) gstart[g] = 0;
  } else {
    int prev = batch[n - 1];
    for (int g = prev + 1; g <= cur; g++) gstart[g] = n;
  }
  if (n == N - 1) {
    for (int g = cur + 1; g <= B; g++) gstart[g] = N;
  }
}

// ---------------- CSR: rank via returning atomicAdd (distributed-L2 atomic floor ~22G/s) ---------
__global__ void k_count_rank(const int* __restrict__ dst, int E,
                             int* counts, int* __restrict__ rank) {
  int e = blockIdx.x * blockDim.x + threadIdx.x;
  if (e < E) rank[e] = atomicAdd(&counts[dst[e]], 1);
}

// per-node total (1 self loop + count) -> inclusive block scan
__global__ __launch_bounds__(1024) void k_scan1(const int* __restrict__ counts, int N,
                                                int* __restrict__ row_ptr, int* __restrict__ part) {
  __shared__ int tmp[1024];
  int t = threadIdx.x;
  int i = blockIdx.x * 1024 + t;
  int v = (i < N) ? 1 + counts[i] : 0;
  tmp[t] = v;
  __syncthreads();
  for (int off = 1; off < 1024; off <<= 1) {
    int u = (t >= off) ? tmp[t - off] : 0;
    __syncthreads();
    tmp[t] += u;
    __syncthreads();
  }
  if (i < N) row_ptr[i + 1] = tmp[t];
  if (t == 1023) part[blockIdx.x] = tmp[t];
}

// add prefix of block totals
__global__ __launch_bounds__(1024) void k_scan3(int* __restrict__ row_ptr,
                                                const int* __restrict__ part, int N) {
  __shared__ int s_off;
  int bi = blockIdx.x;
  if (threadIdx.x == 0) {
    int run = 0;
    for (int b = 0; b < bi; b++) run += part[b];
    s_off = run;
    if (bi == 0) row_ptr[0] = 0;
  }
  __syncthreads();
  int i = bi * 1024 + threadIdx.x;
  if (i < N) row_ptr[i + 1] += s_off;
}

// ---------------- fp16-MFMA GEMM body (64-row tile): hb(fp16)=A@W ; s,d ; partial max(s) ---------
__device__ __forceinline__ void gemm_body(char* smem, float* redmax, int bx,
                                          const float* __restrict__ A32,
                                          const unsigned short* __restrict__ A16,
                                          const float* __restrict__ W,
                                          unsigned short* __restrict__ hb,
                                          const float* __restrict__ asrc,
                                          const float* __restrict__ adst,
                                          float* __restrict__ sv, float* __restrict__ dv,
                                          unsigned* __restrict__ maxSlot, int M) {
  _Float16* Ah = (_Float16*)smem;                       // [64][AST]
  _Float16* Wt = (_Float16*)(smem + 64 * AST * 2);      // [128][WST] transposed W
  float*    hS = (float*)(smem + 64 * AST * 2);         // [64][HST] aliases Wt after mfma
  int t = threadIdx.x;
  int rowbase = bx * 64;

  if (A16) {
    for (int i = t; i < 64 * 16; i += 256) {
      int r = i >> 4, c8 = (i & 15) << 3;
      int gr = rowbase + r;
      uint4 v = make_uint4(0u, 0u, 0u, 0u);
      if (gr < M) v = *(const uint4*)&A16[(size_t)gr * 128 + c8];
      *(uint4*)&Ah[r * AST + c8] = v;
    }
  } else {
    for (int i = t; i < 64 * 32; i += 256) {
      int r = i >> 5, c4 = (i & 31) << 2;
      int gr = rowbase + r;
      float4 v = make_float4(0.f, 0.f, 0.f, 0.f);
      if (gr < M) v = *(const float4*)&A32[(size_t)gr * 128 + c4];
      _Float16 tmp[4] = {(_Float16)v.x, (_Float16)v.y, (_Float16)v.z, (_Float16)v.w};
      *(short4*)&Ah[r * AST + c4] = *(short4*)tmp;
    }
  }
  for (int i = t; i < 128 * 32; i += 256) {
    int r = i >> 5, c4 = (i & 31) << 2;
    float4 v = *(const float4*)&W[(size_t)r * 128 + c4];
    Wt[(c4 + 0) * WST + r] = (_Float16)v.x;
    Wt[(c4 + 1) * WST + r] = (_Float16)v.y;
    Wt[(c4 + 2) * WST + r] = (_Float16)v.z;
    Wt[(c4 + 3) * WST + r] = (_Float16)v.w;
  }
  __syncthreads();

  int wave = t >> 6, lane = t & 63, quad = lane >> 4, l15 = lane & 15;
  f32x4v acc[4][2];
#pragma unroll
  for (int mt = 0; mt < 4; mt++)
#pragma unroll
    for (int nt = 0; nt < 2; nt++) {
      acc[mt][nt][0] = 0.f; acc[mt][nt][1] = 0.f; acc[mt][nt][2] = 0.f; acc[mt][nt][3] = 0.f;
    }

#pragma unroll
  for (int s = 0; s < 4; s++) {
    int k0 = (s << 5) + (quad << 3);
    f16x8 af[4], bf[2];
#pragma unroll
    for (int mt = 0; mt < 4; mt++)
      af[mt] = *(f16x8*)&Ah[(mt * 16 + l15) * AST + k0];
#pragma unroll
    for (int nt = 0; nt < 2; nt++)
      bf[nt] = *(f16x8*)&Wt[(wave * 32 + nt * 16 + l15) * WST + k0];
#pragma unroll
    for (int mt = 0; mt < 4; mt++)
#pragma unroll
      for (int nt = 0; nt < 2; nt++)
        acc[mt][nt] = __builtin_amdgcn_mfma_f32_16x16x32_f16(af[mt], bf[nt], acc[mt][nt], 0, 0, 0);
  }
  __syncthreads();

#pragma unroll
  for (int mt = 0; mt < 4; mt++)
#pragma unroll
    for (int nt = 0; nt < 2; nt++)
#pragma unroll
      for (int rr = 0; rr < 4; rr++)
        hS[(mt * 16 + quad * 4 + rr) * HST + wave * 32 + nt * 16 + l15] = acc[mt][nt][rr];
  __syncthreads();

  int tx = t & 31, ty = t >> 5;
  float4 av  = *(const float4*)&asrc[tx * 4];
  float4 adv = *(const float4*)&adst[tx * 4];
  float wmax = -1e30f;
#pragma unroll
  for (int r8 = 0; r8 < 8; r8++) {
    int row = r8 * 8 + ty;
    int gr = rowbase + row;
    float4 hv = *(float4*)&hS[row * HST + tx * 4];
    float ps = hv.x * av.x + hv.y * av.y + hv.z * av.z + hv.w * av.w;
    float pd = hv.x * adv.x + hv.y * adv.y + hv.z * adv.z + hv.w * adv.w;
#pragma unroll
    for (int mask = 16; mask; mask >>= 1) {
      ps += __shfl_xor(ps, mask);
      pd += __shfl_xor(pd, mask);
    }
    if (gr < M) {
      _Float16 hq[4] = {(_Float16)hv.x, (_Float16)hv.y, (_Float16)hv.z, (_Float16)hv.w};
      *(uint2*)&hb[(size_t)gr * 128 + tx * 4] = *(uint2*)hq;
      if (tx == 0) { sv[gr] = ps; dv[gr] = pd; wmax = fmaxf(wmax, ps); }
    }
  }
#pragma unroll
  for (int mask = 32; mask; mask >>= 1) wmax = fmaxf(wmax, __shfl_xor(wmax, mask));
  if ((t & 63) == 0) redmax[t >> 6] = wmax;
  __syncthreads();
  if (t == 0) {
    float mx = fmaxf(fmaxf(redmax[0], redmax[1]), fmaxf(redmax[2], redmax[3]));
    atomicMax(&maxSlot[bx & 255], enc_f(mx));
  }
}

// ---------------- FUSED: CSR fill (scatter) || layer-0 GEMM, interleaved 8:1 --------------------
// gemm tiles at block positions 9k+4 (k < Gg); all other blocks are fill.
__global__ __launch_bounds__(256) void k_fill_gemm(const int* __restrict__ src,
                                                   const int* __restrict__ dst,
                                                   const int* __restrict__ rank, int E, int N,
                                                   const int* __restrict__ row_ptr,
                                                   int* __restrict__ col,
                                                   const float* __restrict__ A32,
                                                   const float* __restrict__ W,
                                                   unsigned short* __restrict__ hb,
                                                   const float* __restrict__ asrc,
                                                   const float* __restrict__ adst,
                                                   float* __restrict__ sv, float* __restrict__ dv,
                                                   unsigned* __restrict__ maxSlot, int Gg) {
  __shared__ __align__(16) char smem[SMEM_BYTES];
  __shared__ float redmax[4];
  int b = (int)blockIdx.x;
  bool isGemm = ((b % 9) == 4) && ((b / 9) < Gg);
  if (isGemm) {
    gemm_body(smem, redmax, b / 9, A32, (const unsigned short*)nullptr, W,
              hb, asrc, adst, sv, dv, maxSlot, N);
  } else {
    int nGemmBefore = (b >= 4) ? min((b - 4) / 9 + 1, Gg) : 0;
    int i = (b - nGemmBefore) * 256 + threadIdx.x;
    if (i < N) col[row_ptr[i]] = i;  // self loop first in each row
    int e = i - N;
    if (e >= 0 && e < E) col[row_ptr[dst[e]] + 1 + rank[e]] = src[e];
  }
}

// ---------------- standalone fused GEMM for layers 1,2 ----------------
__global__ __launch_bounds__(256) void k_gemm_fused(const unsigned short* __restrict__ A16,
                                                    const float* __restrict__ W,
                                                    unsigned short* __restrict__ hb,
                                                    const float* __restrict__ asrc,
                                                    const float* __restrict__ adst,
                                                    float* __restrict__ sv, float* __restrict__ dv,
                                                    unsigned* __restrict__ maxSlot, int M) {
  __shared__ __align__(16) char smem[SMEM_BYTES];
  __shared__ float redmax[4];
  gemm_body(smem, redmax, (int)blockIdx.x, (const float*)nullptr, A16, W,
            hb, asrc, adst, sv, dv, maxSlot, M);
}

// ---------------- segment-softmax aggregation: 1 wave/node, 4 groups, 3-deep prefetch ------------
__global__ __launch_bounds__(256) void k_agg(const unsigned short* __restrict__ hb,
                                             const float* __restrict__ sv,
                                             const float* __restrict__ dv,
                                             const int* __restrict__ row_ptr,
                                             const int* __restrict__ col,
                                             const float* __restrict__ bias,
                                             const unsigned* __restrict__ maxSlot,
                                             unsigned short* __restrict__ out16,
                                             int N, int relu) {
  int wid = (int)((blockIdx.x * (size_t)blockDim.x + threadIdx.x) >> 6);
  int lane = threadIdx.x & 63;
  if (wid >= N) return;

  unsigned mp = max(max(maxSlot[lane], maxSlot[lane + 64]),
                    max(maxSlot[lane + 128], maxSlot[lane + 192]));
#pragma unroll
  for (int off = 32; off; off >>= 1) mp = max(mp, __shfl_xor(mp, off));
  float maxS = dec_f(mp);

  int beg = row_ptr[wid], end = row_ptr[wid + 1];
  float dn = dv[wid];
  float m = maxS + dn;
  m = (m > 0.f) ? m : NEG_SLOPE * m;  // upper bound on all incoming e (leaky_relu monotone)

  int g = lane >> 4, sub = lane & 15;
  const uint32_t* hbu = (const uint32_t*)hb;
  float acc[8];
#pragma unroll
  for (int k = 0; k < 8; k++) acc[k] = 0.f;
  float dsum = 0.f;

  // 3-deep software pipeline: 3 independent (w, h-row) gathers in flight per 16-lane group
  int j = beg + g;
  float w0 = 0.f, w1 = 0.f, w2 = 0.f;
  uint4 h0 = make_uint4(0u, 0u, 0u, 0u);
  uint4 h1 = make_uint4(0u, 0u, 0u, 0u);
  uint4 h2 = make_uint4(0u, 0u, 0u, 0u);
  if (j < end) {
    int sn = col[j];
    float e = sv[sn] + dn;
    e = (e > 0.f) ? e : NEG_SLOPE * e;
    w0 = __expf(e - m);
    h0 = *(const uint4*)(hbu + (size_t)sn * 64 + sub * 4);
  }
  if (j + 4 < end) {
    int sn = col[j + 4];
    float e = sv[sn] + dn;
    e = (e > 0.f) ? e : NEG_SLOPE * e;
    w1 = __expf(e - m);
    h1 = *(const uint4*)(hbu + (size_t)sn * 64 + sub * 4);
  }
  if (j + 8 < end) {
    int sn = col[j + 8];
    float e = sv[sn] + dn;
    e = (e > 0.f) ? e : NEG_SLOPE * e;
    w2 = __expf(e - m);
    h2 = *(const uint4*)(hbu + (size_t)sn * 64 + sub * 4);
  }
  j += 12;
  while (j < end) {
    dsum += w0;
    {
      const _Float16* hp = (const _Float16*)&h0;
#pragma unroll
      for (int k = 0; k < 8; k++) acc[k] += w0 * (float)hp[k];
    }
    w0 = w1; h0 = h1;
    w1 = w2; h1 = h2;
    int sn = col[j];
    float e = sv[sn] + dn;
    e = (e > 0.f) ? e : NEG_SLOPE * e;
    w2 = __expf(e - m);
    h2 = *(const uint4*)(hbu + (size_t)sn * 64 + sub * 4);
    j += 4;
  }
  {
    dsum += w0;
    const _Float16* hp = (const _Float16*)&h0;
#pragma unroll
    for (int k = 0; k < 8; k++) acc[k] += w0 * (float)hp[k];
  }
  {
    dsum += w1;
    const _Float16* hp = (const _Float16*)&h1;
#pragma unroll
    for (int k = 0; k < 8; k++) acc[k] += w1 * (float)hp[k];
  }
  {
    dsum += w2;
    const _Float16* hp = (const _Float16*)&h2;
#pragma unroll
    for (int k = 0; k < 8; k++) acc[k] += w2 * (float)hp[k];
  }

  dsum += __shfl_xor(dsum, 16);
  dsum += __shfl_xor(dsum, 32);
#pragma unroll
  for (int k = 0; k < 8; k++) {
    acc[k] += __shfl_xor(acc[k], 16);
    acc[k] += __shfl_xor(acc[k], 32);
  }
  if (lane < 16) {
    float inv = 1.f / dsum;
    float o[8];
    const float* bp = &bias[sub * 8];
#pragma unroll
    for (int k = 0; k < 8; k++) {
      o[k] = acc[k] * inv + bp[k];
      if (relu) o[k] = fmaxf(o[k], 0.f);
    }
    _Float16 q[8];
#pragma unroll
    for (int k = 0; k < 8; k++) q[k] = (_Float16)o[k];
    *(uint4*)&out16[(size_t)wid * 128 + sub * 8] = *(uint4*)q;
  }
}

// ---------------- mean pool (fp16 in) + relu, 4-way node-segment split ----------------
__global__ __launch_bounds__(256) void k_pool(const unsigned short* __restrict__ h16,
                                              const int* __restrict__ gstart,
                                              float* __restrict__ pooled, int B) {
  __shared__ float red[4][128];
  int b = blockIdx.x, t = threadIdx.x;
  int c = t & 63, seg = t >> 6;
  int s0 = gstart[b], s1 = gstart[b + 1];
  int cnt = s1 - s0;
  int per = (cnt + 3) >> 2;
  int n0 = s0 + seg * per;
  int n1 = min(n0 + per, s1);
  const uint32_t* hu = (const uint32_t*)h16;
  float a0 = 0.f, a1 = 0.f;
  for (int n = n0; n < n1; n++) {
    union { uint32_t u; _Float16 h[2]; } cv;
    cv.u = hu[(size_t)n * 64 + c];
    a0 += (float)cv.h[0];
    a1 += (float)cv.h[1];
  }
  if (seg) { red[seg][2 * c] = a0; red[seg][2 * c + 1] = a1; }
  __syncthreads();
  if (seg == 0) {
    a0 += red[1][2 * c] + red[2][2 * c] + red[3][2 * c];
    a1 += red[1][2 * c + 1] + red[2][2 * c + 1] + red[3][2 * c + 1];
    float inv = 1.f / (float)(cnt > 0 ? cnt : 1);
    pooled[b * 128 + 2 * c]     = fmaxf(a0 * inv, 0.f);
    pooled[b * 128 + 2 * c + 1] = fmaxf(a1 * inv, 0.f);
  }
}

// ---------------- fused MLP head ----------------
__global__ __launch_bounds__(256) void k_mlp(const float* __restrict__ pooled,
                                             const float* __restrict__ Wf1,
                                             const float* __restrict__ bf1,
                                             const float* __restrict__ Wf2,
                                             const float* __restrict__ bf2,
                                             float* __restrict__ out, int B) {
  __shared__ float P[4][128];
  __shared__ float H1[4][1024];
  __shared__ float R[4][128];
  int t = threadIdx.x;
  int g0 = blockIdx.x * 4;

  for (int i = t; i < 4 * 128; i += 256) {
    int gi = i >> 7, c = i & 127;
    P[gi][c] = (g0 + gi < B) ? pooled[(size_t)(g0 + gi) * 128 + c] : 0.f;
  }
  __syncthreads();

#pragma unroll
  for (int cb = 0; cb < 4; cb++) {
    int c = cb * 256 + t;
    float a0 = 0.f, a1 = 0.f, a2 = 0.f, a3 = 0.f;
    for (int k = 0; k < 128; k++) {
      float w = Wf1[(size_t)k * 1024 + c];
      a0 += P[0][k] * w; a1 += P[1][k] * w; a2 += P[2][k] * w; a3 += P[3][k] * w;
    }
    float b = bf1[c];
    H1[0][c] = fmaxf(a0 + b, 0.f);
    H1[1][c] = fmaxf(a1 + b, 0.f);
    H1[2][c] = fmaxf(a2 + b, 0.f);
    H1[3][c] = fmaxf(a3 + b, 0.f);
  }
  __syncthreads();

  int c = t & 127, hh = t >> 7;
  float a0 = 0.f, a1 = 0.f, a2 = 0.f, a3 = 0.f;
  int k0 = hh * 512;
  for (int k = k0; k < k0 + 512; k++) {
    float w = Wf2[(size_t)k * 128 + c];
    a0 += H1[0][k] * w; a1 += H1[1][k] * w; a2 += H1[2][k] * w; a3 += H1[3][k] * w;
  }
  if (hh == 1) { R[0][c] = a0; R[1][c] = a1; R[2][c] = a2; R[3][c] = a3; }
  __syncthreads();
  if (hh == 0) {
    float b = bf2[c];
    float o0 = a0 + R[0][c] + b;
    float o1 = a1 + R[1][c] + b;
    float o2 = a2 + R[2][c] + b;
    float o3 = a3 + R[3][c] + b;
    if (g0 + 0 < B) out[(size_t)(g0 + 0) * 128 + c] = o0;
    if (g0 + 1 < B) out[(size_t)(g0 + 1) * 128 + c] = o1;
    if (g0 + 2 < B) out[(size_t)(g0 + 2) * 128 + c] = o2;
    if (g0 + 3 < B) out[(size_t)(g0 + 3) * 128 + c] = o3;
  }
}

extern "C" void kernel_launch(void* const* d_in, const int* in_sizes, int n_in,
                              void* d_out, int out_size, void* d_ws, size_t ws_size,
                              hipStream_t stream) {
  const float* x     = (const float*)d_in[0];
  const int*   ei    = (const int*)d_in[1];
  const int*   batch = (const int*)d_in[3];
  const float* W1 = (const float*)d_in[4];
  const float* as1 = (const float*)d_in[5];
  const float* ad1 = (const float*)d_in[6];
  const float* b1 = (const float*)d_in[7];
  const float* W2 = (const float*)d_in[8];
  const float* as2 = (const float*)d_in[9];
  const float* ad2 = (const float*)d_in[10];
  const float* b2 = (const float*)d_in[11];
  const float* W3 = (const float*)d_in[12];
  const float* as3 = (const float*)d_in[13];
  const float* ad3 = (const float*)d_in[14];
  const float* b3 = (const float*)d_in[15];
  const float* Wf1 = (const float*)d_in[16];
  const float* bf1 = (const float*)d_in[17];
  const float* Wf2 = (const float*)d_in[18];
  const float* bf2 = (const float*)d_in[19];

  const int N = in_sizes[0] / 128;
  const int E = in_sizes[1] / 2;
  const int B = out_size / 128;

  char* base_ws = (char*)d_ws;
  size_t off = 0;
  auto carve = [&](size_t bytes) -> void* {
    off = (off + 255) & ~(size_t)255;
    void* p = base_ws + off;
    off += bytes;
    return p;
  };
  int* counts   = (int*)carve((size_t)N * 4);
  int* row_ptr  = (int*)carve((size_t)(N + 1) * 4);
  int* rank     = (int*)carve((size_t)E * 4);
  int* col      = (int*)carve((size_t)(E + N) * 4);
  int* part     = (int*)carve(1024 * 4);
  int* gstart   = (int*)carve((size_t)(B + 1) * 4);
  unsigned* maxPart = (unsigned*)carve(768 * 4);
  float* sbuf   = (float*)carve((size_t)N * 4);
  float* dbuf   = (float*)carve((size_t)N * 4);
  unsigned short* hb  = (unsigned short*)carve((size_t)N * 128 * 2);
  unsigned short* a16 = (unsigned short*)carve((size_t)N * 128 * 2);
  float* pooled = (float*)carve((size_t)B * 128 * 4);

  const int* srcp = ei;
  const int* dstp = ei + E;
  const int nb = (N + 1023) / 1024;
  const int Gg = (N + 63) / 64;                 // gemm tiles per layer
  const int Gf = (E + N + 255) / 256;           // fill blocks

  hipLaunchKernelGGL(k_bounds, dim3((N + 255) / 256), dim3(256), 0, stream,
                     batch, N, B, gstart, maxPart, counts);
  hipLaunchKernelGGL(k_count_rank, dim3((E + 255) / 256), dim3(256), 0, stream,
                     dstp, E, counts, rank);
  hipLaunchKernelGGL(k_scan1, dim3(nb), dim3(1024), 0, stream, counts, N, row_ptr, part);
  hipLaunchKernelGGL(k_scan3, dim3(nb), dim3(1024), 0, stream, row_ptr, part, N);

  // fill (CSR scatter) || gemm layer 0 — independent, interleaved in one grid
  hipLaunchKernelGGL(k_fill_gemm, dim3(Gf + Gg), dim3(256), 0, stream,
                     srcp, dstp, rank, E, N, row_ptr, col,
                     x, W1, hb, as1, ad1, sbuf, dbuf, maxPart + 0 * 256, Gg);

  hipLaunchKernelGGL(k_agg, dim3((N + 3) / 4), dim3(256), 0, stream,
                     hb, sbuf, dbuf, row_ptr, col, b1, maxPart + 0 * 256, a16, N, 0);

  hipLaunchKernelGGL(k_gemm_fused, dim3(Gg), dim3(256), 0, stream,
                     a16, W2, hb, as2, ad2, sbuf, dbuf, maxPart + 1 * 256, N);
  hipLaunchKernelGGL(k_agg, dim3((N + 3) / 4), dim3(256), 0, stream,
                     hb, sbuf, dbuf, row_ptr, col, b2, maxPart + 1 * 256, a16, N, 1);

  hipLaunchKernelGGL(k_gemm_fused, dim3(Gg), dim3(256), 0, stream,
                     a16, W3, hb, as3, ad3, sbuf, dbuf, maxPart + 2 * 256, N);
  hipLaunchKernelGGL(k_agg, dim3((N + 3) / 4), dim3(256), 0, stream,
                     hb, sbuf, dbuf, row_ptr, col, b3, maxPart + 2 * 256, a16, N, 1);

  hipLaunchKernelGGL(k_pool, dim3(B), dim3(256), 0, stream, a16, gstart, pooled, B);
  hipLaunchKernelGGL(k_mlp, dim3((B + 3) / 4), dim3(256), 0, stream,
                     pooled, Wf1, bf1, Wf2, bf2, (float*)d_out, B);
}